// Round 11
// baseline (8979.569 us; speedup 1.0000x reference)
//
#include <hip/hip_runtime.h>
#include <hip/hip_bf16.h>

typedef __attribute__((ext_vector_type(8))) short bhalf8;
typedef __attribute__((ext_vector_type(4))) float fvec4;
typedef __attribute__((ext_vector_type(4))) unsigned u32x4;

static __device__ __forceinline__ unsigned short f2bf(float f) {
  unsigned u = __builtin_bit_cast(unsigned, f);
  u = (u + 0x7fffu + ((u >> 16) & 1u)) >> 16;   // round-to-nearest-even
  return (unsigned short)u;
}
static __device__ __forceinline__ float tanh_fast(float x) {
  x = fminf(12.f, fmaxf(-12.f, x));
  float e = __expf(2.f * x);
  return (e - 1.f) / (e + 1.f);
}
static __device__ __forceinline__ fvec4 tanh4(fvec4 v) {
  fvec4 r;
  r[0] = tanh_fast(v[0]); r[1] = tanh_fast(v[1]);
  r[2] = tanh_fast(v[2]); r[3] = tanh_fast(v[3]);
  return r;
}
static __device__ __forceinline__ bhalf8 load_w8(const float* p) {
  fvec4 a = *(const fvec4*)p;
  fvec4 b = *(const fvec4*)(p + 4);
  bhalf8 r;
  r[0] = (short)f2bf(a[0]); r[1] = (short)f2bf(a[1]);
  r[2] = (short)f2bf(a[2]); r[3] = (short)f2bf(a[3]);
  r[4] = (short)f2bf(b[0]); r[5] = (short)f2bf(b[1]);
  r[6] = (short)f2bf(b[2]); r[7] = (short)f2bf(b[3]);
  return r;
}

// ---- two data tiers ----
// fabric (sc0 sc1): coherence at MALL. Proven rounds 4/7/9. Used for flags ALWAYS,
//   and for data when a group spans XCDs.
// L2 (plain stores + sc0 loads): coherence at the single XCD-local L2 — valid only
//   when the whole group is runtime-VERIFIED to sit on one XCD.
// SESSION RULES: asm-load windows <= 16 x u32x4, crossing at most the 8-MFMA Win
// block (rounds 6/7 proven); flags/polls never change tier (round-5 lesson).
static __device__ __forceinline__ void st_short_coh(unsigned short* p, unsigned v) {
  asm volatile("global_store_short %0, %1, off sc0 sc1" :: "v"(p), "v"(v) : "memory");
}
static __device__ __forceinline__ void st_short_l2(unsigned short* p, unsigned v) {
  asm volatile("global_store_short %0, %1, off" :: "v"(p), "v"(v) : "memory");
}
static __device__ __forceinline__ void st_f32_coh(float* p, float v) {
  asm volatile("global_store_dword %0, %1, off sc0 sc1" :: "v"(p), "v"(v) : "memory");
}
static __device__ __forceinline__ void st_u32_coh(unsigned* p, unsigned v) {
  asm volatile("global_store_dword %0, %1, off sc0 sc1" :: "v"(p), "v"(v) : "memory");
}
static __device__ __forceinline__ u32x4 ld16_l2(const void* p) {
  u32x4 v;
  asm volatile("global_load_dwordx4 %0, %1, off sc0" : "=v"(v) : "v"(p) : "memory");
  return v;
}
static __device__ __forceinline__ unsigned ld_u32_coh(const unsigned* p) {
  unsigned v;
  asm volatile("global_load_dword %0, %1, off sc0 sc1\n\ts_waitcnt vmcnt(0)"
               : "=v"(v) : "v"(p) : "memory");
  return v;
}
static __device__ __forceinline__ float ld_f32_coh(const float* p) {
  float v;
  asm volatile("global_load_dword %0, %1, off sc0 sc1\n\ts_waitcnt vmcnt(0)"
               : "=v"(v) : "v"(p) : "memory");
  return v;
}
// direct global->LDS, 16B/lane, CPol 0x11 = SC0|SC1 (fabric tier; round-9 proven).
static __device__ __forceinline__ void gll16_coh(const void* g, void* lds) {
  __builtin_amdgcn_global_load_lds(
      (const __attribute__((address_space(1))) void*)g,
      (__attribute__((address_space(3))) void*)lds, 16, 0, 0x11);
}

#define MFMA16(a, b, c) __builtin_amdgcn_mfma_f32_16x16x32_bf16((a), (b), (c), 0, 0, 0)

// Persistent kernel, 256 WGs x 256 thr, 1 WG/CU -> grid HW-resident, spin safe.
// Group mapping targets round-robin bid->XCD: members of a group = bids {x+8k}.
// Placement VERIFIED at runtime (pre-step over the proven flag protocol); groups on
// one XCD exchange z12/z2 through that XCD's L2; others fall back to fabric tier.
extern "C" __global__ void __launch_bounds__(256, 1)
alarm_rnn_persist(const float* __restrict__ X, const float* __restrict__ Win1,
                  const float* __restrict__ bin1, const float* __restrict__ Wrec1,
                  const float* __restrict__ Win2, const float* __restrict__ bin2,
                  const float* __restrict__ Wrec2, const float* __restrict__ Wout,
                  const float* __restrict__ bout, float* __restrict__ out,
                  unsigned* sync, unsigned short* gbuf0, unsigned short* gbuf1,
                  unsigned short* z2b0, unsigned short* z2b1, float* z1buf)
{
  constexpr int kL = 512, kI = 256, kH = 1024;
  // LDS: [0,64K) z12 | [64K,128K) z2 | [128K,160K) X ping-pong (2 x 16K)
  extern __shared__ char smem[];

  unsigned* flags = sync;          // [0,256): per-WG step flags (fabric tier ALWAYS)
  unsigned* pflags = sync + 256;   // [256,512): pre-step flags
  unsigned* xcds = sync + 512;     // [512,768): per-WG XCD ids

  const int tid = threadIdx.x, bid = blockIdx.x;
  const int slot = bid >> 3;
  const int grp = (bid & 7) * 2 + (slot >> 4);  // 16 groups
  const int memb = slot & 15;                   // 16 members
  const int lane = tid & 63, w = tid >> 6;
  const int row16 = lane & 15, kq = lane >> 4;
  const int sw = (row16 & 7) << 4;
  const int hcol = memb * 64 + w * 16 + row16;
  const int brow0 = grp * 32;

  // ---- one-time: weights -> registers ----
  bhalf8 w1[32], w2[32], wi1[8], wi2[8];
  {
    const float* p1 = Wrec1 + (size_t)hcol * kH + kq * 8;
    const float* p2 = Wrec2 + (size_t)hcol * kH + kq * 8;
#pragma unroll
    for (int kk = 0; kk < 32; ++kk) {
      w1[kk] = load_w8(p1 + kk * 32);
      w2[kk] = load_w8(p2 + kk * 32);
    }
    const float* q1 = Win1 + (size_t)hcol * kI + kq * 8;
    const float* q2 = Win2 + (size_t)hcol * kI + kq * 8;
#pragma unroll
    for (int kk = 0; kk < 8; ++kk) {
      wi1[kk] = load_w8(q1 + kk * 32);
      wi2[kk] = load_w8(q2 + kk * 32);
    }
  }
  const float bv1 = bin1[hcol];
  const float bv2 = bin2[hcol];
  fvec4 z2c0 = {0.f, 0.f, 0.f, 0.f}, z2c1 = {0.f, 0.f, 0.f, 0.f};

  // ---- pre-step: exchange XCD ids over the PROVEN tier+protocol; derive mode ----
  unsigned myxcd;
  asm volatile("s_getreg_b32 %0, hwreg(HW_REG_XCC_ID)" : "=s"(myxcd));
  myxcd &= 0xF;
  if (tid == 0) {
    st_u32_coh(xcds + grp * 16 + memb, myxcd);
    asm volatile("s_waitcnt vmcnt(0)" ::: "memory");
    st_u32_coh(pflags + grp * 16 + memb, 1u);
  }
  {
    const unsigned* fp = pflags + grp * 16 + (lane & 15);
    for (;;) {
      unsigned v = (lane < 16) ? ld_u32_coh(fp) : 1u;
      bool ok = (lane >= 16) || (v >= 1u);
      if (__all(ok)) break;
      __builtin_amdgcn_s_sleep(1);
    }
  }
  bool l2m;
  {
    unsigned v = (lane < 16) ? ld_u32_coh(xcds + grp * 16 + (lane & 15)) : myxcd;
    l2m = __all(v == myxcd);   // group-uniform: same data, same computation
  }

  // ---- prologue: stage X(0) -> Xbuf0, X(1) -> Xbuf1 ----
  {
    int r = tid >> 3, q = tid & 7;
#pragma unroll
    for (int p = 0; p < 2; ++p) {
      const float* xp = X + (size_t)(brow0 + r) * (kL * kI) + (size_t)p * kI;
      fvec4 xv[8];
#pragma unroll
      for (int j = 0; j < 8; ++j) xv[j] = *(const fvec4*)(xp + q * 4 + j * 32);
#pragma unroll
      for (int j = 0; j < 8; ++j) {
        int i0 = q * 4 + j * 32;
        ushort4 pk;
        pk.x = f2bf(xv[j][0]); pk.y = f2bf(xv[j][1]);
        pk.z = f2bf(xv[j][2]); pk.w = f2bf(xv[j][3]);
        *(ushort4*)(smem + 131072 + p * 16384 + (r << 9) + ((i0 * 2) ^ ((r & 7) << 4))) = pk;
      }
    }
  }
  __syncthreads();

  for (int l = 0; l < kL; ++l) {
    const bool even = ((l & 1) == 0);
    const int e = l >> 1;
    const unsigned short* zsrc = (l & 1) ? gbuf1 : gbuf0;
    const unsigned short* z2src = (e & 1) ? z2b1 : z2b0;
    const char* xb = smem + 131072 + ((l & 1) << 14);

    fvec4 acc0 = {bv1, bv1, bv1, bv1}, acc1 = acc0;
    fvec4 c2a0 = {bv2, bv2, bv2, bv2}, c2a1 = c2a0;

    if (l2m) {
      // ======== L2 tier: register staging (sc0 loads), plain stores ========
      u32x4 ztmp[16];
#pragma unroll
      for (int it = 0; it < 16; ++it) {
        int c = it * 256 + tid;
        int r = c >> 7, cb = (c & 127) * 16;
        ztmp[it] = ld16_l2((const char*)zsrc + (((size_t)(brow0 + r)) << 11) + cb);
      }
#pragma unroll
      for (int kk = 0; kk < 8; ++kk) {     // Win1*X under the z12 load shadow
        int cb = kk * 64 + kq * 16;
        bhalf8 a0 = *(const bhalf8*)(xb + (row16 << 9) + (cb ^ sw));
        bhalf8 a1 = *(const bhalf8*)(xb + ((16 + row16) << 9) + (cb ^ sw));
        acc0 = MFMA16(a0, wi1[kk], acc0);
        acc1 = MFMA16(a1, wi1[kk], acc1);
      }
      __builtin_amdgcn_sched_barrier(0);
      asm volatile("s_waitcnt vmcnt(0)" ::: "memory");
      __builtin_amdgcn_sched_barrier(0);
#pragma unroll
      for (int it = 0; it < 16; ++it) {
        int c = it * 256 + tid;
        int r = c >> 7, cb = (c & 127) * 16;
        *(u32x4*)(smem + (r << 11) + (cb ^ ((r & 7) << 4))) = ztmp[it];
      }
      if (even) {
        u32x4 z2t[16];
#pragma unroll
        for (int it = 0; it < 16; ++it) {
          int c = it * 256 + tid;
          int r = c >> 7, cb = (c & 127) * 16;
          z2t[it] = ld16_l2((const char*)z2src + (((size_t)(brow0 + r)) << 11) + cb);
        }
#pragma unroll
        for (int kk = 0; kk < 8; ++kk) {   // Win2*X under the z2 load shadow
          int cb = kk * 64 + kq * 16;
          bhalf8 a0 = *(const bhalf8*)(xb + (row16 << 9) + (cb ^ sw));
          bhalf8 a1 = *(const bhalf8*)(xb + ((16 + row16) << 9) + (cb ^ sw));
          c2a0 = MFMA16(a0, wi2[kk], c2a0);
          c2a1 = MFMA16(a1, wi2[kk], c2a1);
        }
        __builtin_amdgcn_sched_barrier(0);
        asm volatile("s_waitcnt vmcnt(0)" ::: "memory");
        __builtin_amdgcn_sched_barrier(0);
#pragma unroll
        for (int it = 0; it < 16; ++it) {
          int c = it * 256 + tid;
          int r = c >> 7, cb = (c & 127) * 16;
          *(u32x4*)(smem + 65536 + (r << 11) + (cb ^ ((r & 7) << 4))) = z2t[it];
        }
      }
    } else {
      // ======== fabric tier: round-9 path (gll, source-swizzled) ========
#pragma unroll
      for (int it = 0; it < 16; ++it) {
        int c = ((it * 4 + w) << 6) + lane;
        int r = c >> 7, cbs = (c & 127) * 16;
        gll16_coh((const char*)zsrc + (((size_t)(brow0 + r)) << 11) + (cbs ^ ((r & 7) << 4)),
                  smem + ((it * 4 + w) << 10));
      }
      if (even) {
#pragma unroll
        for (int it = 0; it < 16; ++it) {
          int c = ((it * 4 + w) << 6) + lane;
          int r = c >> 7, cbs = (c & 127) * 16;
          gll16_coh((const char*)z2src + (((size_t)(brow0 + r)) << 11) + (cbs ^ ((r & 7) << 4)),
                    smem + 65536 + ((it * 4 + w) << 10));
        }
      }
      __builtin_amdgcn_sched_barrier(0);
#pragma unroll
      for (int kk = 0; kk < 8; ++kk) {
        int cb = kk * 64 + kq * 16;
        bhalf8 a0 = *(const bhalf8*)(xb + (row16 << 9) + (cb ^ sw));
        bhalf8 a1 = *(const bhalf8*)(xb + ((16 + row16) << 9) + (cb ^ sw));
        acc0 = MFMA16(a0, wi1[kk], acc0);
        acc1 = MFMA16(a1, wi1[kk], acc1);
      }
      if (even) {
#pragma unroll
        for (int kk = 0; kk < 8; ++kk) {
          int cb = kk * 64 + kq * 16;
          bhalf8 a0 = *(const bhalf8*)(xb + (row16 << 9) + (cb ^ sw));
          bhalf8 a1 = *(const bhalf8*)(xb + ((16 + row16) << 9) + (cb ^ sw));
          c2a0 = MFMA16(a0, wi2[kk], c2a0);
          c2a1 = MFMA16(a1, wi2[kk], c2a1);
        }
      }
      asm volatile("s_waitcnt vmcnt(0)" ::: "memory");
      __builtin_amdgcn_sched_barrier(0);
    }
    __syncthreads();  // #1: staged tiles visible

    // ---- B1: z1 = tanh(acc + Wrec1 * z12) ----
#pragma unroll
    for (int kk = 0; kk < 32; ++kk) {
      int cb = kk * 64 + kq * 16;
      bhalf8 a0 = *(const bhalf8*)(smem + (row16 << 11) + (cb ^ sw));
      bhalf8 a1 = *(const bhalf8*)(smem + ((16 + row16) << 11) + (cb ^ sw));
      acc0 = MFMA16(a0, w1[kk], acc0);
      acc1 = MFMA16(a1, w1[kk], acc1);
    }
    fvec4 z1n0 = tanh4(acc0), z1n1 = tanh4(acc1);

    // ---- B2 (even): z2 = tanh(c2a + Wrec2 * z2prev) ----
    if (even) {
#pragma unroll
      for (int kk = 0; kk < 32; ++kk) {
        int cb = kk * 64 + kq * 16;
        bhalf8 a0 = *(const bhalf8*)(smem + 65536 + (row16 << 11) + (cb ^ sw));
        bhalf8 a1 = *(const bhalf8*)(smem + 65536 + ((16 + row16) << 11) + (cb ^ sw));
        c2a0 = MFMA16(a0, w2[kk], c2a0);
        c2a1 = MFMA16(a1, w2[kk], c2a1);
      }
      z2c0 = tanh4(c2a0);
      z2c1 = tanh4(c2a1);
    }

    // ---- C: publish z12 = z1+z2 (and z2 on even); drain; flag (fabric ALWAYS) ----
    if (l < kL - 1) {
      unsigned short* dst = (l & 1) ? gbuf0 : gbuf1;
      if (l2m) {
#pragma unroll
        for (int i = 0; i < 4; ++i) {
          st_short_l2(dst + (size_t)(brow0 + kq * 4 + i) * kH + hcol, f2bf(z1n0[i] + z2c0[i]));
          st_short_l2(dst + (size_t)(brow0 + 16 + kq * 4 + i) * kH + hcol, f2bf(z1n1[i] + z2c1[i]));
        }
      } else {
#pragma unroll
        for (int i = 0; i < 4; ++i) {
          st_short_coh(dst + (size_t)(brow0 + kq * 4 + i) * kH + hcol, f2bf(z1n0[i] + z2c0[i]));
          st_short_coh(dst + (size_t)(brow0 + 16 + kq * 4 + i) * kH + hcol, f2bf(z1n1[i] + z2c1[i]));
        }
      }
    } else {
#pragma unroll
      for (int i = 0; i < 4; ++i) {  // final z1: fabric tier always (epilogue reads MALL)
        st_f32_coh(z1buf + (size_t)(brow0 + kq * 4 + i) * kH + hcol, z1n0[i]);
        st_f32_coh(z1buf + (size_t)(brow0 + 16 + kq * 4 + i) * kH + hcol, z1n1[i]);
      }
    }
    if (even) {
      unsigned short* z2dst = (e & 1) ? z2b0 : z2b1;
      if (l2m) {
#pragma unroll
        for (int i = 0; i < 4; ++i) {
          st_short_l2(z2dst + (size_t)(brow0 + kq * 4 + i) * kH + hcol, f2bf(z2c0[i]));
          st_short_l2(z2dst + (size_t)(brow0 + 16 + kq * 4 + i) * kH + hcol, f2bf(z2c1[i]));
        }
      } else {
#pragma unroll
        for (int i = 0; i < 4; ++i) {
          st_short_coh(z2dst + (size_t)(brow0 + kq * 4 + i) * kH + hcol, f2bf(z2c0[i]));
          st_short_coh(z2dst + (size_t)(brow0 + 16 + kq * 4 + i) * kH + hcol, f2bf(z2c1[i]));
        }
      }
    }
    asm volatile("s_waitcnt vmcnt(0)" ::: "memory");
    __syncthreads();  // #2: all waves' exchange stores drained
    if (tid == 0) st_u32_coh(flags + grp * 16 + memb, (unsigned)(l + 1));

    // ---- D: X(l+2) -> Xbuf[l&1] (post-flag slack) ----
    if (l + 2 < kL) {
      const int xr = tid >> 3, xq = tid & 7;
      const float* xp = X + (size_t)(brow0 + xr) * (kL * kI) + (size_t)(l + 2) * kI;
      fvec4 xv[8];
#pragma unroll
      for (int j = 0; j < 8; ++j) xv[j] = *(const fvec4*)(xp + xq * 4 + j * 32);
#pragma unroll
      for (int j = 0; j < 8; ++j) {
        int i0 = xq * 4 + j * 32;
        ushort4 pk;
        pk.x = f2bf(xv[j][0]); pk.y = f2bf(xv[j][1]);
        pk.z = f2bf(xv[j][2]); pk.w = f2bf(xv[j][3]);
        *(ushort4*)(smem + 131072 + ((l & 1) << 14) + (xr << 9) + ((i0 * 2) ^ ((xr & 7) << 4))) = pk;
      }
    }

    // ---- F: poll sibling flags (fabric tier; proven) ----
    {
      const unsigned tgt = (unsigned)(l + 1);
      const unsigned* fp = flags + grp * 16 + (lane & 15);
      for (;;) {
        unsigned v = (lane < 16) ? ld_u32_coh(fp) : tgt;
        bool ok = (lane >= 16) || ((lane & 15) == memb) || (v >= tgt);
        if (__all(ok)) break;
        __builtin_amdgcn_s_sleep(1);
      }
      __builtin_amdgcn_sched_barrier(0);
    }
  }

  // ---- epilogue: out[b] = tanh(z1[b,:] . Wout + bout), one WG per group ----
  if (memb == 0) {
    int r = tid >> 3, q = tid & 7;
    const float* zr = z1buf + (size_t)(brow0 + r) * kH;
    float s = 0.f;
    for (int h = q * 128; h < q * 128 + 128; ++h) s += ld_f32_coh(zr + h) * Wout[h];
    s += __shfl_xor(s, 1);
    s += __shfl_xor(s, 2);
    s += __shfl_xor(s, 4);
    if (q == 0) out[brow0 + r] = tanh_fast(s + bout[0]);
  }
}

extern "C" void kernel_launch(void* const* d_in, const int* in_sizes, int n_in,
                              void* d_out, int out_size, void* d_ws, size_t ws_size,
                              hipStream_t stream) {
  const float* X = (const float*)d_in[0];
  const float* Win1 = (const float*)d_in[1];
  const float* bin1 = (const float*)d_in[2];
  const float* Wrec1 = (const float*)d_in[3];
  const float* Win2 = (const float*)d_in[4];
  const float* bin2 = (const float*)d_in[5];
  const float* Wrec2 = (const float*)d_in[6];
  const float* Wout = (const float*)d_in[7];
  const float* bout = (const float*)d_in[8];
  float* out = (float*)d_out;

  char* ws = (char*)d_ws;
  unsigned* sync = (unsigned*)ws;                                    // flags|pflags|xcds
  unsigned short* gbuf0 = (unsigned short*)(ws + 4096);              // 1 MB z12 ping
  unsigned short* gbuf1 = (unsigned short*)(ws + 4096 + (1 << 20));  // 1 MB z12 pong
  unsigned short* z2b0 = (unsigned short*)(ws + 4096 + (2 << 20));   // 1 MB z2 ping
  unsigned short* z2b1 = (unsigned short*)(ws + 4096 + (3 << 20));   // 1 MB z2 pong
  float* z1buf = (float*)(ws + 4096 + (4 << 20));                    // 2 MB final z1 (f32)

  (void)hipMemsetAsync(sync, 0, 4096, stream);
  (void)hipMemsetAsync(gbuf0, 0, (size_t)512 * 1024 * 2, stream);  // z12(l=0) = 0
  (void)hipMemsetAsync(z2b0, 0, (size_t)512 * 1024 * 2, stream);   // z2(l=0)  = 0

  (void)hipFuncSetAttribute((const void*)alarm_rnn_persist,
                            hipFuncAttributeMaxDynamicSharedMemorySize, 163840);

  alarm_rnn_persist<<<dim3(256), dim3(256), 163840, stream>>>(
      X, Win1, bin1, Wrec1, Win2, bin2, Wrec2, Wout, bout, out,
      sync, gbuf0, gbuf1, z2b0, z2b1, z1buf);
}

// Round 12
// 5479.295 us; speedup vs baseline: 1.6388x; 1.6388x over previous
//
#include <hip/hip_runtime.h>
#include <hip/hip_bf16.h>

typedef __attribute__((ext_vector_type(8))) short bhalf8;
typedef __attribute__((ext_vector_type(4))) float fvec4;
typedef __attribute__((ext_vector_type(4))) unsigned u32x4;

static __device__ __forceinline__ unsigned short f2bf(float f) {
  unsigned u = __builtin_bit_cast(unsigned, f);
  u = (u + 0x7fffu + ((u >> 16) & 1u)) >> 16;   // round-to-nearest-even
  return (unsigned short)u;
}
static __device__ __forceinline__ float tanh_fast(float x) {
  x = fminf(12.f, fmaxf(-12.f, x));
  float e = __expf(2.f * x);
  return (e - 1.f) / (e + 1.f);
}
static __device__ __forceinline__ fvec4 tanh4(fvec4 v) {
  fvec4 r;
  r[0] = tanh_fast(v[0]); r[1] = tanh_fast(v[1]);
  r[2] = tanh_fast(v[2]); r[3] = tanh_fast(v[3]);
  return r;
}
static __device__ __forceinline__ bhalf8 load_w8(const float* p) {
  fvec4 a = *(const fvec4*)p;
  fvec4 b = *(const fvec4*)(p + 4);
  bhalf8 r;
  r[0] = (short)f2bf(a[0]); r[1] = (short)f2bf(a[1]);
  r[2] = (short)f2bf(a[2]); r[3] = (short)f2bf(a[3]);
  r[4] = (short)f2bf(b[0]); r[5] = (short)f2bf(b[1]);
  r[6] = (short)f2bf(b[2]); r[7] = (short)f2bf(b[3]);
  return r;
}

// ---- fabric-coherent (sc0 sc1) accesses: the ONLY tier proven coherent AND fast-
// ---- path-safe on this part (rounds 4/9; r5/r11 L2-tier attempts both failed).
// ---- SESSION RULES: (1) no asm-load destination window may cross a 32-MFMA GEMM
// ---- (r6 stale data, r8 abort); (2) exchange staging uses global_load_lds (zero
// ---- VGPR window); (3) flags/polls always fused-vmcnt sc0sc1.
static __device__ __forceinline__ void st_f32_coh(float* p, float v) {
  asm volatile("global_store_dword %0, %1, off sc0 sc1" :: "v"(p), "v"(v) : "memory");
}
static __device__ __forceinline__ void st_u32_coh(unsigned* p, unsigned v) {
  asm volatile("global_store_dword %0, %1, off sc0 sc1" :: "v"(p), "v"(v) : "memory");
}
static __device__ __forceinline__ void st16_coh(void* p, u32x4 v) {
  asm volatile("global_store_dwordx4 %0, %1, off sc0 sc1" :: "v"(p), "v"(v) : "memory");
}
static __device__ __forceinline__ unsigned ld_u32_coh(const unsigned* p) {
  unsigned v;
  asm volatile("global_load_dword %0, %1, off sc0 sc1\n\ts_waitcnt vmcnt(0)"
               : "=v"(v) : "v"(p) : "memory");
  return v;
}
static __device__ __forceinline__ float ld_f32_coh(const float* p) {
  float v;
  asm volatile("global_load_dword %0, %1, off sc0 sc1\n\ts_waitcnt vmcnt(0)"
               : "=v"(v) : "v"(p) : "memory");
  return v;
}
// direct global->LDS, 16B/lane, CPol 0x11 = SC0|SC1 (bypass L1 + XCD-L2).
static __device__ __forceinline__ void gll16_coh(const void* g, void* lds) {
  __builtin_amdgcn_global_load_lds(
      (const __attribute__((address_space(1))) void*)g,
      (__attribute__((address_space(3))) void*)lds, 16, 0, 0x11);
}

#define MFMA16(a, b, c) __builtin_amdgcn_mfma_f32_16x16x32_bf16((a), (b), (c), 0, 0, 0)

// Persistent kernel, 256 WGs x 256 thr, 1 WG/CU -> grid HW-resident, spin safe.
// WG=(grp: 32 batch rows, memb: 64 H-cols). Round-9 structure; this round adds:
//  (a) exchange stores coalesced via LDS transpose -> one 16B store/thread
//  (b) member-staggered staging order to spread MALL multicast pressure.
extern "C" __global__ void __launch_bounds__(256, 1)
alarm_rnn_persist(const float* __restrict__ X, const float* __restrict__ Win1,
                  const float* __restrict__ bin1, const float* __restrict__ Wrec1,
                  const float* __restrict__ Win2, const float* __restrict__ bin2,
                  const float* __restrict__ Wrec2, const float* __restrict__ Wout,
                  const float* __restrict__ bout, float* __restrict__ out,
                  unsigned* flags, unsigned short* gbuf0, unsigned short* gbuf1,
                  unsigned short* z2b0, unsigned short* z2b1, float* z1buf)
{
  constexpr int kL = 512, kI = 256, kH = 1024;
  // LDS: [0,64K) z12 (also reused [0,8K) for store-transpose) | [64K,128K) z2
  //      | [128K,160K) X ping-pong (2 x 16K)
  extern __shared__ char smem[];

  const int tid = threadIdx.x, bid = blockIdx.x;
  const int grp = bid >> 4, memb = bid & 15;
  const int lane = tid & 63, w = tid >> 6;
  const int row16 = lane & 15, kq = lane >> 4;
  const int sw = (row16 & 7) << 4;
  const int hcol = memb * 64 + w * 16 + row16;
  const int brow0 = grp * 32;

  // ---- one-time: weights -> registers (B-fragment: lane holds W[hcol, kq*8+j (+32*kk)]) ----
  bhalf8 w1[32], w2[32], wi1[8], wi2[8];
  {
    const float* p1 = Wrec1 + (size_t)hcol * kH + kq * 8;
    const float* p2 = Wrec2 + (size_t)hcol * kH + kq * 8;
#pragma unroll
    for (int kk = 0; kk < 32; ++kk) {
      w1[kk] = load_w8(p1 + kk * 32);
      w2[kk] = load_w8(p2 + kk * 32);
    }
    const float* q1 = Win1 + (size_t)hcol * kI + kq * 8;
    const float* q2 = Win2 + (size_t)hcol * kI + kq * 8;
#pragma unroll
    for (int kk = 0; kk < 8; ++kk) {
      wi1[kk] = load_w8(q1 + kk * 32);
      wi2[kk] = load_w8(q2 + kk * 32);
    }
  }
  const float bv1 = bin1[hcol];
  const float bv2 = bin2[hcol];
  fvec4 z2c0 = {0.f, 0.f, 0.f, 0.f}, z2c1 = {0.f, 0.f, 0.f, 0.f};

  // ---- prologue: stage X(0) -> Xbuf0, X(1) -> Xbuf1 ----
  {
    int r = tid >> 3, q = tid & 7;
#pragma unroll
    for (int p = 0; p < 2; ++p) {
      const float* xp = X + (size_t)(brow0 + r) * (kL * kI) + (size_t)p * kI;
      fvec4 xv[8];
#pragma unroll
      for (int j = 0; j < 8; ++j) xv[j] = *(const fvec4*)(xp + q * 4 + j * 32);
#pragma unroll
      for (int j = 0; j < 8; ++j) {
        int i0 = q * 4 + j * 32;
        ushort4 pk;
        pk.x = f2bf(xv[j][0]); pk.y = f2bf(xv[j][1]);
        pk.z = f2bf(xv[j][2]); pk.w = f2bf(xv[j][3]);
        *(ushort4*)(smem + 131072 + p * 16384 + (r << 9) + ((i0 * 2) ^ ((r & 7) << 4))) = pk;
      }
    }
  }
  __syncthreads();

  for (int l = 0; l < kL; ++l) {
    const bool even = ((l & 1) == 0);
    const int e = l >> 1;

    // ---- A1: issue z12 (and z2 on even) global->LDS; order staggered by memb ----
    {
      const unsigned short* zsrc = (l & 1) ? gbuf1 : gbuf0;
#pragma unroll
      for (int it = 0; it < 16; ++it) {
        int itx = (it + memb) & 15;                  // stagger start across members
        int c = ((itx * 4 + w) << 6) + lane;
        int r = c >> 7, cbs = (c & 127) * 16;
        gll16_coh((const char*)zsrc + (((size_t)(brow0 + r)) << 11) + (cbs ^ ((r & 7) << 4)),
                  smem + ((itx * 4 + w) << 10));
      }
      if (even) {
        const unsigned short* z2src = (e & 1) ? z2b1 : z2b0;
#pragma unroll
        for (int it = 0; it < 16; ++it) {
          int itx = (it + memb) & 15;
          int c = ((itx * 4 + w) << 6) + lane;
          int r = c >> 7, cbs = (c & 127) * 16;
          gll16_coh((const char*)z2src + (((size_t)(brow0 + r)) << 11) + (cbs ^ ((r & 7) << 4)),
                    smem + 65536 + ((itx * 4 + w) << 10));
        }
      }
      __builtin_amdgcn_sched_barrier(0);  // keep issues above the MFMA shadow
    }

    // ---- A2: Win1*X(l) (+ Win2*X(l) on even) under the load shadow ----
    const char* xb = smem + 131072 + ((l & 1) << 14);
    fvec4 acc0 = {bv1, bv1, bv1, bv1}, acc1 = acc0;
#pragma unroll
    for (int kk = 0; kk < 8; ++kk) {
      int cb = kk * 64 + kq * 16;
      bhalf8 a0 = *(const bhalf8*)(xb + (row16 << 9) + (cb ^ sw));
      bhalf8 a1 = *(const bhalf8*)(xb + ((16 + row16) << 9) + (cb ^ sw));
      acc0 = MFMA16(a0, wi1[kk], acc0);
      acc1 = MFMA16(a1, wi1[kk], acc1);
    }
    fvec4 c2a0 = {bv2, bv2, bv2, bv2}, c2a1 = c2a0;
    if (even) {
#pragma unroll
      for (int kk = 0; kk < 8; ++kk) {
        int cb = kk * 64 + kq * 16;
        bhalf8 a0 = *(const bhalf8*)(xb + (row16 << 9) + (cb ^ sw));
        bhalf8 a1 = *(const bhalf8*)(xb + ((16 + row16) << 9) + (cb ^ sw));
        c2a0 = MFMA16(a0, wi2[kk], c2a0);
        c2a1 = MFMA16(a1, wi2[kk], c2a1);
      }
    }
    // ---- A3: staged data complete -> visible to all waves ----
    asm volatile("s_waitcnt vmcnt(0)" ::: "memory");
    __builtin_amdgcn_sched_barrier(0);
    __syncthreads();  // #1

    // ---- B1: z1 = tanh(acc + Wrec1 * z12) ----
#pragma unroll
    for (int kk = 0; kk < 32; ++kk) {
      int cb = kk * 64 + kq * 16;
      bhalf8 a0 = *(const bhalf8*)(smem + (row16 << 11) + (cb ^ sw));
      bhalf8 a1 = *(const bhalf8*)(smem + ((16 + row16) << 11) + (cb ^ sw));
      acc0 = MFMA16(a0, w1[kk], acc0);
      acc1 = MFMA16(a1, w1[kk], acc1);
    }
    fvec4 z1n0 = tanh4(acc0), z1n1 = tanh4(acc1);

    // ---- B2 (even): z2 = tanh(c2a + Wrec2 * z2prev) ----
    if (even) {
#pragma unroll
      for (int kk = 0; kk < 32; ++kk) {
        int cb = kk * 64 + kq * 16;
        bhalf8 a0 = *(const bhalf8*)(smem + 65536 + (row16 << 11) + (cb ^ sw));
        bhalf8 a1 = *(const bhalf8*)(smem + 65536 + ((16 + row16) << 11) + (cb ^ sw));
        c2a0 = MFMA16(a0, w2[kk], c2a0);
        c2a1 = MFMA16(a1, w2[kk], c2a1);
      }
      z2c0 = tanh4(c2a0);
      z2c1 = tanh4(c2a1);
    }

    // ---- C: coalesced publish via LDS transpose (values bit-identical to r9) ----
    __syncthreads();  // #1.5: all GEMM reads of z12/z2 LDS regions complete
    if (l < kL - 1) {
      const int colb = (w * 16 + row16) * 2;  // byte col within this WG's 64-col tile
#pragma unroll
      for (int i = 0; i < 4; ++i) {
        int r0 = kq * 4 + i, r1 = 16 + kq * 4 + i;
        *(unsigned short*)(smem + r0 * 128 + (colb ^ ((r0 & 7) << 4))) = f2bf(z1n0[i] + z2c0[i]);
        *(unsigned short*)(smem + r1 * 128 + (colb ^ ((r1 & 7) << 4))) = f2bf(z1n1[i] + z2c1[i]);
      }
      if (even) {
#pragma unroll
        for (int i = 0; i < 4; ++i) {
          int r0 = kq * 4 + i, r1 = 16 + kq * 4 + i;
          *(unsigned short*)(smem + 4096 + r0 * 128 + (colb ^ ((r0 & 7) << 4))) = f2bf(z2c0[i]);
          *(unsigned short*)(smem + 4096 + r1 * 128 + (colb ^ ((r1 & 7) << 4))) = f2bf(z2c1[i]);
        }
      }
      __syncthreads();  // #1.75: transpose tiles complete
      {
        int r = tid >> 3, s = tid & 7;
        u32x4 v = *(const u32x4*)(smem + r * 128 + ((s * 16) ^ ((r & 7) << 4)));
        unsigned short* dst = (l & 1) ? gbuf0 : gbuf1;
        st16_coh((char*)dst + (((size_t)(brow0 + r)) << 11) + memb * 128 + s * 16, v);
        if (even) {
          u32x4 v2 = *(const u32x4*)(smem + 4096 + r * 128 + ((s * 16) ^ ((r & 7) << 4)));
          unsigned short* z2dst = (e & 1) ? z2b0 : z2b1;
          st16_coh((char*)z2dst + (((size_t)(brow0 + r)) << 11) + memb * 128 + s * 16, v2);
        }
      }
    } else {
      // final step: f32 z1, scattered (runs once; epilogue reads it back)
#pragma unroll
      for (int i = 0; i < 4; ++i) {
        st_f32_coh(z1buf + (size_t)(brow0 + kq * 4 + i) * kH + hcol, z1n0[i]);
        st_f32_coh(z1buf + (size_t)(brow0 + 16 + kq * 4 + i) * kH + hcol, z1n1[i]);
      }
    }
    asm volatile("s_waitcnt vmcnt(0)" ::: "memory");
    __syncthreads();  // #2: all waves' exchange stores drained
    if (tid == 0) st_u32_coh(flags + grp * 16 + memb, (unsigned)(l + 1));

    // ---- D: X(l+2) -> Xbuf[l&1] (post-flag slack; normal cached loads) ----
    if (l + 2 < kL) {
      const int xr = tid >> 3, xq = tid & 7;
      const float* xp = X + (size_t)(brow0 + xr) * (kL * kI) + (size_t)(l + 2) * kI;
      fvec4 xv[8];
#pragma unroll
      for (int j = 0; j < 8; ++j) xv[j] = *(const fvec4*)(xp + xq * 4 + j * 32);
#pragma unroll
      for (int j = 0; j < 8; ++j) {
        int i0 = xq * 4 + j * 32;
        ushort4 pk;
        pk.x = f2bf(xv[j][0]); pk.y = f2bf(xv[j][1]);
        pk.z = f2bf(xv[j][2]); pk.w = f2bf(xv[j][3]);
        *(ushort4*)(smem + 131072 + ((l & 1) << 14) + (xr << 9) + ((i0 * 2) ^ ((xr & 7) << 4))) = pk;
      }
    }

    // ---- F: poll sibling flags for step l+1 ----
    {
      const unsigned tgt = (unsigned)(l + 1);
      const unsigned* fp = flags + grp * 16 + (lane & 15);
      for (;;) {
        unsigned v = (lane < 16) ? ld_u32_coh(fp) : tgt;
        bool ok = (lane >= 16) || ((lane & 15) == memb) || (v >= tgt);
        if (__all(ok)) break;
        __builtin_amdgcn_s_sleep(1);
      }
      __builtin_amdgcn_sched_barrier(0);
    }
  }

  // ---- epilogue: out[b] = tanh(z1[b,:] . Wout + bout), one WG per group ----
  // fused-vmcnt loads (rounds 4/7/9 proven; no deferred-load register window)
  if (memb == 0) {
    int r = tid >> 3, q = tid & 7;
    const float* zr = z1buf + (size_t)(brow0 + r) * kH;
    float s = 0.f;
    for (int h = q * 128; h < q * 128 + 128; ++h) s += ld_f32_coh(zr + h) * Wout[h];
    s += __shfl_xor(s, 1);
    s += __shfl_xor(s, 2);
    s += __shfl_xor(s, 4);
    if (q == 0) out[brow0 + r] = tanh_fast(s + bout[0]);
  }
}

extern "C" void kernel_launch(void* const* d_in, const int* in_sizes, int n_in,
                              void* d_out, int out_size, void* d_ws, size_t ws_size,
                              hipStream_t stream) {
  const float* X = (const float*)d_in[0];
  const float* Win1 = (const float*)d_in[1];
  const float* bin1 = (const float*)d_in[2];
  const float* Wrec1 = (const float*)d_in[3];
  const float* Win2 = (const float*)d_in[4];
  const float* bin2 = (const float*)d_in[5];
  const float* Wrec2 = (const float*)d_in[6];
  const float* Wout = (const float*)d_in[7];
  const float* bout = (const float*)d_in[8];
  float* out = (float*)d_out;

  char* ws = (char*)d_ws;
  unsigned* flags = (unsigned*)ws;                                   // 256 dwords
  unsigned short* gbuf0 = (unsigned short*)(ws + 4096);              // 1 MB z12 ping
  unsigned short* gbuf1 = (unsigned short*)(ws + 4096 + (1 << 20));  // 1 MB z12 pong
  unsigned short* z2b0 = (unsigned short*)(ws + 4096 + (2 << 20));   // 1 MB z2 ping
  unsigned short* z2b1 = (unsigned short*)(ws + 4096 + (3 << 20));   // 1 MB z2 pong
  float* z1buf = (float*)(ws + 4096 + (4 << 20));                    // 2 MB final z1 (f32)

  (void)hipMemsetAsync(flags, 0, 4096, stream);
  (void)hipMemsetAsync(gbuf0, 0, (size_t)512 * 1024 * 2, stream);  // z12(l=0) = 0
  (void)hipMemsetAsync(z2b0, 0, (size_t)512 * 1024 * 2, stream);   // z2(l=0)  = 0

  (void)hipFuncSetAttribute((const void*)alarm_rnn_persist,
                            hipFuncAttributeMaxDynamicSharedMemorySize, 163840);

  alarm_rnn_persist<<<dim3(256), dim3(256), 163840, stream>>>(
      X, Win1, bin1, Wrec1, Win2, bin2, Wrec2, Wout, bout, out,
      flags, gbuf0, gbuf1, z2b0, z2b1, z1buf);
}